// Round 11
// baseline (214.519 us; speedup 1.0000x reference)
//
#include <hip/hip_runtime.h>
#include <cstdint>
#include <cstddef>

#define BB 16
#define CC 512
#define NN 4096

typedef __attribute__((ext_vector_type(4))) float f32x4;
typedef __attribute__((ext_vector_type(8))) _Float16 f16x8;

#define VMCNT(n) asm volatile("s_waitcnt vmcnt(" #n ")" ::: "memory")

__device__ __forceinline__ unsigned short f2h(float f) {
  _Float16 h = (_Float16)f;                       // v_cvt_f16_f32, RTN
  return __builtin_bit_cast(unsigned short, h);
}
__device__ __forceinline__ float h2f(unsigned short u) {
  return (float)__builtin_bit_cast(_Float16, u);
}
__device__ __forceinline__ unsigned int pk2(float a, float b) {
  return (unsigned int)f2h(a) | ((unsigned int)f2h(b) << 16);
}

// async global->LDS, 16B per lane. LDS dest must be wave-uniform base; HW adds lane*16.
__device__ __forceinline__ void gload16(const unsigned short* g, short* l) {
  __builtin_amdgcn_global_load_lds(
      (const __attribute__((address_space(1))) unsigned int*)g,
      (__attribute__((address_space(3))) unsigned int*)(__attribute__((address_space(3))) short*)l,
      16, 0, 0);
}

// ---------------- Kernel A: x -> fp16 q, transposed q, row partial sums ---------------
// 4096 blocks, ~17 KB LDS -> 8 blocks/CU. G13: lane owns 8 consecutive n -> 2x float4
// load + ONE uint4 (16B) qh store; 16-lane-group shfl reduce for row sums.
__global__ __launch_bounds__(256) void k_convert(
    const float* __restrict__ x,
    unsigned short* __restrict__ qh,
    unsigned short* __restrict__ qt,
    float* __restrict__ part)
{
  const int nt = blockIdx.x;     // 32 tiles of 128 n
  const int ct = blockIdx.y;     // 8 tiles of 64 c
  const int b  = blockIdx.z;
  const int c0 = ct << 6;
  const int n0 = nt << 7;
  const int t  = threadIdx.x;
  const int w  = t >> 6;
  const int l  = t & 63;

  __shared__ unsigned short lt[128 * 65];   // [n_local][c_local], pitch 65
  __shared__ float fs[64];                  // per-row sums

  const size_t xb = (size_t)b * CC * NN;
  const int n8 = (l & 15) << 3;             // 8 consecutive n per lane

  #pragma unroll
  for (int i = 0; i < 4; ++i) {
    const int r = (i << 4) + (w << 2) + (l >> 4);      // c row in tile, 64 distinct
    const size_t off = xb + (size_t)(c0 + r) * NN + n0 + n8;
    const float4 v0 = *(const float4*)(x + off);
    const float4 v1 = *(const float4*)(x + off + 4);
    uint4 pkv;
    pkv.x = pk2(v0.x, v0.y);
    pkv.y = pk2(v0.z, v0.w);
    pkv.z = pk2(v1.x, v1.y);
    pkv.w = pk2(v1.z, v1.w);
    *(uint4*)(qh + off) = pkv;                         // 16 B store
    lt[(n8 + 0) * 65 + r] = (unsigned short)(pkv.x & 0xffff);
    lt[(n8 + 1) * 65 + r] = (unsigned short)(pkv.x >> 16);
    lt[(n8 + 2) * 65 + r] = (unsigned short)(pkv.y & 0xffff);
    lt[(n8 + 3) * 65 + r] = (unsigned short)(pkv.y >> 16);
    lt[(n8 + 4) * 65 + r] = (unsigned short)(pkv.z & 0xffff);
    lt[(n8 + 5) * 65 + r] = (unsigned short)(pkv.z >> 16);
    lt[(n8 + 6) * 65 + r] = (unsigned short)(pkv.w & 0xffff);
    lt[(n8 + 7) * 65 + r] = (unsigned short)(pkv.w >> 16);
    float s = (v0.x + v0.y) + (v0.z + v0.w) + (v1.x + v1.y) + (v1.z + v1.w);
    s += __shfl_xor(s, 1);
    s += __shfl_xor(s, 2);
    s += __shfl_xor(s, 4);
    s += __shfl_xor(s, 8);                             // sum over the 16-lane row group
    if ((l & 15) == 0) fs[r] = s;
  }
  __syncthreads();
  if (t < 64) part[((size_t)b * CC + c0 + t) * 32 + nt] = fs[t];

  // transposed write: qt[b][n][c]
  #pragma unroll
  for (int p = 0; p < 4; ++p) {
    const int n   = (p << 5) + (t >> 3);
    const int cc8 = (t & 7) << 3;
    const unsigned short* e = &lt[n * 65 + cc8];
    uint4 pk;
    pk.x = (unsigned)e[0] | ((unsigned)e[1] << 16);
    pk.y = (unsigned)e[2] | ((unsigned)e[3] << 16);
    pk.z = (unsigned)e[4] | ((unsigned)e[5] << 16);
    pk.w = (unsigned)e[6] | ((unsigned)e[7] << 16);
    *(uint4*)(qt + ((size_t)b * NN + n0 + n) * CC + c0 + cc8) = pk;
  }
}

// ---------------- Kernel A2: sum row partials -> pooled_x raw sums --------------------
__global__ __launch_bounds__(256) void k_sumpart(const float* __restrict__ part,
                                                 float* __restrict__ px)
{
  const int g = blockIdx.x * 256 + threadIdx.x;   // 0..8191 = b*512+c
  float s = 0.f;
  #pragma unroll
  for (int i = 0; i < 32; ++i) s += part[(size_t)g * 32 + i];
  px[g] = s;
}

// ---------------- Kernel B: energy = q.qT, fp16, SYMMETRIC upper-tri ------------------
// 128x128 tile, 4 waves, BK=32, 48 KiB LDS (3 blocks/CU). Depth-2 pipeline (3 bufs):
// VMCNT(4) before each barrier -> stage(kk+1) landed for all waves; stage(kk+2) stays
// in flight across the barrier (T4, sound cross-wave).
template <int KSPLIT>
__global__ __launch_bounds__(256, 3) void k_energy(
    const unsigned short* __restrict__ qh,
    float* __restrict__ EP)
{
  const int bx  = blockIdx.x;               // 160*KSPLIT blocks
  const int xcd = bx & 7;
  const int j   = bx >> 3;
  const int gi  = j / 10;
  const int t10 = j % 10;
  const int g   = xcd + (gi << 3);          // group = b*KSPLIT+ks, grouped per XCD
  const int b   = g / KSPLIT;
  const int ks  = g % KSPLIT;
  int tr, tc;
  if (t10 < 4)      { tr = 0; tc = t10; }
  else if (t10 < 7) { tr = 1; tc = t10 - 3; }
  else if (t10 < 9) { tr = 2; tc = t10 - 5; }
  else              { tr = 3; tc = 3; }
  const bool diag = (tr == tc);
  const int kbase = ks * (NN / KSPLIT);
  const int NK    = 128 / KSPLIT;           // K-steps of 32

  const int t = threadIdx.x, w = t >> 6, l = t & 63;
  const int wr = w >> 1, wc = w & 1;

  __shared__ short lds[3][2][128 * 32];     // [buf][A,B] = 48 KiB

  const size_t qoff = (size_t)b * CC * NN;
  const unsigned short* sA = qh + qoff + (size_t)(tr * 128) * NN;
  const unsigned short* sB = diag ? sA : qh + qoff + (size_t)(tc * 128) * NN;

  const int r1 = w * 16 + (l >> 2);
  const int kl = (((l & 3) ^ (l >> 4)) << 3);          // pre-swizzled source k offset
  const int d1 = w * 512;
  const int d2 = 2048 + w * 512;
  const int laneoff = ((l & 15) << 5) + ((((l >> 4) ^ ((l >> 2) & 3))) << 3);

  f32x4 acc[4][4] = {};

  auto stage = [&](int buf, int kk) {       // always 4 loads (uniform vmcnt)
    const int k0 = kbase + kk * 32 + kl;
    gload16(sA + (size_t)r1 * NN + k0,        &lds[buf][0][d1]);
    gload16(sA + (size_t)(r1 + 64) * NN + k0, &lds[buf][0][d2]);
    gload16(sB + (size_t)r1 * NN + k0,        &lds[buf][1][d1]);
    gload16(sB + (size_t)(r1 + 64) * NN + k0, &lds[buf][1][d2]);
  };

  stage(0, 0);
  stage(1, 1);
  VMCNT(4);
  __builtin_amdgcn_s_barrier();

  for (int kk = 0; kk < NK; ++kk) {
    const int cur = kk % 3;
    if (kk + 2 < NK) stage((kk + 2) % 3, kk + 2);
    const short* A = &lds[cur][0][0];
    const short* Bm = &lds[cur][1][0];
    f16x8 ah[4], bh[4];
    #pragma unroll
    for (int m = 0; m < 4; ++m)
      ah[m] = *(const f16x8*)(A + (wr * 64 + m * 16) * 32 + laneoff);
    #pragma unroll
    for (int n = 0; n < 4; ++n)
      bh[n] = *(const f16x8*)(Bm + (wc * 64 + n * 16) * 32 + laneoff);
    __builtin_amdgcn_s_setprio(1);
    #pragma unroll
    for (int m = 0; m < 4; ++m)
      #pragma unroll
      for (int n = 0; n < 4; ++n)
        acc[m][n] = __builtin_amdgcn_mfma_f32_16x16x32_f16(ah[m], bh[n], acc[m][n], 0, 0, 0);
    __builtin_amdgcn_s_setprio(0);
    if (kk + 2 < NK)      VMCNT(4);
    else if (kk + 1 < NK) VMCNT(0);
    __builtin_amdgcn_s_barrier();
  }

  const int row0 = tr * 128 + wr * 64, col0 = tc * 128 + wc * 64;
  float* Eb = EP + ((size_t)ks * BB + b) * CC * CC;
  #pragma unroll
  for (int m = 0; m < 4; ++m)
    #pragma unroll
    for (int n = 0; n < 4; ++n)
      #pragma unroll
      for (int r = 0; r < 4; ++r) {
        const int row = row0 + m * 16 + ((l >> 4) << 2) + r;
        const int col = col0 + n * 16 + (l & 15);
        const float v = acc[m][n][r];
        Eb[(size_t)row * CC + col] = v;
        if (!diag) Eb[(size_t)col * CC + row] = v;
      }
}

// ---------------- Kernel C: att = softmax(-E) per row; pooled_out = att . mean_x ------
// G13: float4 loads of E/px (16 B/lane), one uint4 store of 8 packed fp16.
template <int NP>
__global__ __launch_bounds__(64) void k_softmax(
    const float* __restrict__ EP, const float* __restrict__ px,
    unsigned short* __restrict__ att, float* __restrict__ po)
{
  const int bx = blockIdx.x;                  // 8192 = b*512+c
  const int b = bx >> 9, c = bx & 511;
  const int l = threadIdx.x;
  const size_t row4 = (((size_t)b * CC + c) * CC) >> 2;   // float4 index of row start
  const size_t PS4 = ((size_t)BB * CC * CC) >> 2;
  const float4* E4 = (const float4*)EP;

  float v[8];
  {
    float4 a = E4[row4 + 2 * l];
    float4 bq = E4[row4 + 2 * l + 1];
    #pragma unroll
    for (int p = 1; p < NP; ++p) {
      const float4 a2 = E4[(size_t)p * PS4 + row4 + 2 * l];
      const float4 b2 = E4[(size_t)p * PS4 + row4 + 2 * l + 1];
      a.x += a2.x; a.y += a2.y; a.z += a2.z; a.w += a2.w;
      bq.x += b2.x; bq.y += b2.y; bq.z += b2.z; bq.w += b2.w;
    }
    v[0] = a.x; v[1] = a.y; v[2] = a.z; v[3] = a.w;
    v[4] = bq.x; v[5] = bq.y; v[6] = bq.z; v[7] = bq.w;
  }
  float mn = v[0];
  #pragma unroll
  for (int i = 1; i < 8; ++i) mn = fminf(mn, v[i]);
  #pragma unroll
  for (int o = 32; o > 0; o >>= 1) mn = fminf(mn, __shfl_xor(mn, o));
  float s = 0.f;
  #pragma unroll
  for (int i = 0; i < 8; ++i) { v[i] = __expf(mn - v[i]); s += v[i]; }
  float dot;
  {
    const float4* px4 = (const float4*)(px + (size_t)b * CC);
    const float4 p0 = px4[2 * l];
    const float4 p1 = px4[2 * l + 1];
    dot = v[0] * p0.x + v[1] * p0.y + v[2] * p0.z + v[3] * p0.w
        + v[4] * p1.x + v[5] * p1.y + v[6] * p1.z + v[7] * p1.w;
  }
  #pragma unroll
  for (int o = 32; o > 0; o >>= 1) { s += __shfl_xor(s, o); dot += __shfl_xor(dot, o); }
  const float inv = 1.f / s;
  uint4 pkv;
  pkv.x = pk2(v[0] * inv, v[1] * inv);
  pkv.y = pk2(v[2] * inv, v[3] * inv);
  pkv.z = pk2(v[4] * inv, v[5] * inv);
  pkv.w = pk2(v[6] * inv, v[7] * inv);
  ((uint4*)(att + ((size_t)b * CC + c) * CC))[l] = pkv;   // 16 B store, 8 halves
  if (l == 0) po[(size_t)b * CC + c] = dot / (s * 4096.f);
}

// ---------------- Kernel D: SE MLP -> se[b][c] -----------------------------------------
__global__ __launch_bounds__(256) void k_mlp(
    const float* __restrict__ px, const float* __restrict__ po,
    const float* __restrict__ w1, const float* __restrict__ b1,
    const float* __restrict__ w2, const float* __restrict__ b2,
    float* __restrict__ se)
{
  const int b = blockIdx.x, t = threadIdx.x;
  __shared__ float p[1024];
  __shared__ float hp[64][5];
  __shared__ float h[64];
  for (int i = t; i < 1024; i += 256)
    p[i] = (i < 512) ? px[(size_t)b * 512 + i] * (1.f / 4096.f)
                     : po[(size_t)b * 512 + i - 512];
  __syncthreads();
  {
    const int j = t >> 2, q = t & 3;
    float s = 0.f;
    const float* wr = w1 + (size_t)j * 1024 + q * 256;
    const float* pp = p + q * 256;
    for (int k = 0; k < 256; ++k) s += pp[k] * wr[k];
    hp[j][q] = s;
  }
  __syncthreads();
  if (t < 64) h[t] = fmaxf(hp[t][0] + hp[t][1] + hp[t][2] + hp[t][3] + b1[t], 0.f);
  __syncthreads();
  for (int c = t; c < 512; c += 256) {
    float s = b2[c];
    for (int j = 0; j < 64; ++j) s += h[j] * w2[(size_t)c * 64 + j];
    se[(size_t)b * 512 + c] = 1.f / (1.f + __expf(-s));
  }
}

// ---------------- Kernel E: out = att @ q, fused blend se*x + (1-se)*out --------------
// 8-wave (512t) 128x256 tile, 1024 blocks, LDS 3x24KB=72KB -> 2 blocks/CU.
// Depth-2 pipeline: 3 gload16/wave/stage; VMCNT(3) before each barrier. Blend reads qh.
__global__ __launch_bounds__(512, 4) void k_out(
    const unsigned short* __restrict__ att,
    const unsigned short* __restrict__ qt,
    const float* __restrict__ se,
    const unsigned short* __restrict__ qh,
    float* __restrict__ out)
{
  const int bx = blockIdx.x;                      // 1024 blocks, XCD-grouped per batch
  const int xcd = bx & 7;
  const int j   = bx >> 3;                        // 0..127
  const int b   = xcd + ((j >> 6) << 3);          // 2 batches per XCD
  const int tt  = j & 63;
  const int tr = tt >> 4, tc = tt & 15;           // tr: 4 x 128 c-rows; tc: 16 x 256 n
  const int t = threadIdx.x, w = t >> 6, l = t & 63;
  const int wr = w >> 2, wc = w & 3;              // wave quadrant: 2 x 4 of 64x64

  // [buf][ A:128x32 | B:256x32 ] halves; 12288 halves = 24 KiB per buf
  __shared__ short lds[3][12288];

  const unsigned short* sA = att + (size_t)b * CC * CC + (size_t)(tr * 128) * CC;
  const unsigned short* sB = qt  + (size_t)b * NN * CC + (size_t)(tc * 256) * CC;

  const int r1 = w * 16 + (l >> 2);               // staged row (A: [0,128); B: +0/+128)
  const int kl = (((l & 3) ^ (l >> 4)) << 3);     // pre-swizzled source k offset
  const int dA  = w * 512;                        // wave-uniform LDS half-offsets
  const int dB0 = 4096 + w * 512;
  const int dB1 = 8192 + w * 512;
  const int laneoff = ((l & 15) << 5) + ((((l >> 4) ^ ((l >> 2) & 3))) << 3);

  f32x4 acc[4][4] = {};

  auto stage = [&](int buf, int kk) {             // 3 loads per wave (uniform vmcnt)
    const int k0 = kk * 32 + kl;
    gload16(sA + (size_t)r1 * CC + k0,         &lds[buf][dA]);
    gload16(sB + (size_t)r1 * CC + k0,         &lds[buf][dB0]);
    gload16(sB + (size_t)(r1 + 128) * CC + k0, &lds[buf][dB1]);
  };

  stage(0, 0);
  stage(1, 1);
  VMCNT(3);                                 // stage(0) landed (own wave)
  __builtin_amdgcn_s_barrier();             // -> landed for all waves

  for (int kk = 0; kk < 16; ++kk) {
    const int cur = kk % 3;
    if (kk + 2 < 16) stage((kk + 2) % 3, kk + 2);
    const short* A  = &lds[cur][0];
    const short* Bm = &lds[cur][4096];
    f16x8 af[4], bf[4];
    #pragma unroll
    for (int m = 0; m < 4; ++m) af[m] = *(const f16x8*)(A  + (wr * 64 + m * 16) * 32 + laneoff);
    #pragma unroll
    for (int n = 0; n < 4; ++n) bf[n] = *(const f16x8*)(Bm + (wc * 64 + n * 16) * 32 + laneoff);
    __builtin_amdgcn_s_setprio(1);
    #pragma unroll
    for (int m = 0; m < 4; ++m)
      #pragma unroll
      for (int n = 0; n < 4; ++n)
        acc[m][n] = __builtin_amdgcn_mfma_f32_16x16x32_f16(af[m], bf[n], acc[m][n], 0, 0, 0);
    __builtin_amdgcn_s_setprio(0);
    if (kk + 2 < 16)      VMCNT(3);   // stage(kk+1) landed; stage(kk+2) in flight
    else if (kk + 1 < 16) VMCNT(0);
    __builtin_amdgcn_s_barrier();
  }

  // ---- epilogue: per-wave LDS slab (16 rows x 68 pitch), float4-coalesced IO ----
  float* slab = (float*)(&lds[0][0]) + w * (16 * 68);
  const int row0 = tr * 128 + wr * 64, col0q = tc * 256 + wc * 64;
  const size_t xb = (size_t)b * CC * NN;
  const float* seb = se + (size_t)b * CC;
  #pragma unroll
  for (int m = 0; m < 4; ++m) {
    #pragma unroll
    for (int n = 0; n < 4; ++n)
      #pragma unroll
      for (int r = 0; r < 4; ++r)
        slab[(((l >> 4) << 2) + r) * 68 + n * 16 + (l & 15)] = acc[m][n][r];
    #pragma unroll
    for (int it = 0; it < 4; ++it) {
      const int rl = (it << 2) + (l >> 4);
      const int c  = row0 + m * 16 + rl;
      const int n4 = (l & 15) << 2;
      const float4 a = *(const float4*)&slab[rl * 68 + n4];
      const float sv = seb[c];
      const float om = 1.f - sv;
      const size_t go = xb + (size_t)c * NN + col0q + n4;
      const ushort4 hx = *(const ushort4*)(qh + go);
      float4 o;
      o.x = sv * h2f(hx.x) + om * a.x;
      o.y = sv * h2f(hx.y) + om * a.y;
      o.z = sv * h2f(hx.z) + om * a.z;
      o.w = sv * h2f(hx.w) + om * a.w;
      *(float4*)(out + go) = o;
    }
  }
}

// ---------------------------------------------------------------------------------------
extern "C" void kernel_launch(void* const* d_in, const int* in_sizes, int n_in,
                              void* d_out, int out_size, void* d_ws, size_t ws_size,
                              hipStream_t stream) {
  (void)in_sizes; (void)n_in; (void)out_size;
  const float* x  = (const float*)d_in[0];
  const float* w1 = (const float*)d_in[1];
  const float* b1 = (const float*)d_in[2];
  const float* w2 = (const float*)d_in[3];
  const float* b2 = (const float*)d_in[4];
  float* out = (float*)d_out;

  const size_t O_QH  = 0;                       // 67,108,864 (fp16 q)
  const size_t O_QT  = 67108864;                // 67,108,864 (fp16 qT)
  const size_t O_EP  = 134217728;               // KSPLIT x 16,777,216 (fp32 E partials)
  const size_t EPSZ1 = 16777216;

  // tail: att(8,388,608) + part(1,048,576) + px/po/se(3*32768)
  const size_t TAIL = 8388608 + 1048576 + 3 * 32768;     // 9,535,488
  const size_t NEED1 = O_EP + 1 * EPSZ1 + TAIL;
  const size_t NEED2 = O_EP + 2 * EPSZ1 + TAIL;
  const size_t NEED4 = O_EP + 4 * EPSZ1 + TAIL;

  if (ws_size < NEED1) return;   // fail loudly (output stays poisoned)
  const int ksplit = (ws_size >= NEED4) ? 4 : (ws_size >= NEED2) ? 2 : 1;

  char* ws = (char*)d_ws;
  unsigned short* qh  = (unsigned short*)(ws + O_QH);
  unsigned short* qt  = (unsigned short*)(ws + O_QT);
  float*          EP  = (float*)(ws + O_EP);
  char* tail          = ws + O_EP + (size_t)ksplit * EPSZ1;
  unsigned short* att = (unsigned short*)(tail);
  float*          part= (float*)(tail + 8388608);
  float*          px  = (float*)(tail + 9437184);
  float*          po  = (float*)(tail + 9469952);
  float*          se  = (float*)(tail + 9502720);

  k_convert<<<dim3(32, 8, 16), 256, 0, stream>>>(x, qh, qt, part);
  k_sumpart<<<32, 256, 0, stream>>>(part, px);
  if (ksplit == 4) {
    k_energy<4><<<640, 256, 0, stream>>>(qh, EP);
    k_softmax<4><<<8192, 64, 0, stream>>>(EP, px, att, po);
  } else if (ksplit == 2) {
    k_energy<2><<<320, 256, 0, stream>>>(qh, EP);
    k_softmax<2><<<8192, 64, 0, stream>>>(EP, px, att, po);
  } else {
    k_energy<1><<<160, 256, 0, stream>>>(qh, EP);
    k_softmax<1><<<8192, 64, 0, stream>>>(EP, px, att, po);
  }
  k_mlp<<<16, 256, 0, stream>>>(px, po, w1, b1, w2, b2, se);
  k_out<<<1024, 512, 0, stream>>>(att, qt, se, qh, out);
}

// Round 12
// 184.256 us; speedup vs baseline: 1.1642x; 1.1642x over previous
//
#include <hip/hip_runtime.h>
#include <cstdint>
#include <cstddef>

#define BB 16
#define CC 512
#define NN 4096

typedef __attribute__((ext_vector_type(4))) float f32x4;
typedef __attribute__((ext_vector_type(8))) _Float16 f16x8;
typedef __attribute__((ext_vector_type(2))) unsigned int u32x2;
typedef __attribute__((ext_vector_type(4))) unsigned int u32x4;

#define VMCNT(n) asm volatile("s_waitcnt vmcnt(" #n ")" ::: "memory")
#define TRREAD(dst, p, OFF) \
  asm volatile("ds_read_b64_tr_b16 %0, %1 offset:" #OFF : "=v"(dst) : "v"(p) : "memory")

__device__ __forceinline__ unsigned short f2h(float f) {
  _Float16 h = (_Float16)f;                       // v_cvt_f16_f32, RTN
  return __builtin_bit_cast(unsigned short, h);
}
__device__ __forceinline__ float h2f(unsigned short u) {
  return (float)__builtin_bit_cast(_Float16, u);
}
__device__ __forceinline__ unsigned int pk2(float a, float b) {
  return (unsigned int)f2h(a) | ((unsigned int)f2h(b) << 16);
}

// async global->LDS, 16B per lane. LDS dest must be wave-uniform base; HW adds lane*16.
__device__ __forceinline__ void gload16(const unsigned short* g, short* l) {
  __builtin_amdgcn_global_load_lds(
      (const __attribute__((address_space(1))) unsigned int*)g,
      (__attribute__((address_space(3))) unsigned int*)(__attribute__((address_space(3))) short*)l,
      16, 0, 0);
}

// ---------------- Kernel A: x -> fp16 qh + row partial sums (pure stream) -------------
// qt is GONE: k_out transposes in-LDS via ds_read_b64_tr_b16. -67 MB of stores.
__global__ __launch_bounds__(256) void k_convert(
    const float* __restrict__ x,
    unsigned short* __restrict__ qh,
    float* __restrict__ part)
{
  const int nt = blockIdx.x;     // 32 tiles of 128 n
  const int ct = blockIdx.y;     // 8 tiles of 64 c
  const int b  = blockIdx.z;
  const int c0 = ct << 6;
  const int n0 = nt << 7;
  const int t  = threadIdx.x;
  const int w  = t >> 6;
  const int l  = t & 63;

  __shared__ float fs[64];                  // per-row sums

  const size_t xb = (size_t)b * CC * NN;
  const int n8 = (l & 15) << 3;             // 8 consecutive n per lane

  #pragma unroll
  for (int i = 0; i < 4; ++i) {
    const int r = (i << 4) + (w << 2) + (l >> 4);      // c row in tile, 64 distinct
    const size_t off = xb + (size_t)(c0 + r) * NN + n0 + n8;
    const float4 v0 = *(const float4*)(x + off);
    const float4 v1 = *(const float4*)(x + off + 4);
    uint4 pkv;
    pkv.x = pk2(v0.x, v0.y);
    pkv.y = pk2(v0.z, v0.w);
    pkv.z = pk2(v1.x, v1.y);
    pkv.w = pk2(v1.z, v1.w);
    *(uint4*)(qh + off) = pkv;                         // 16 B store
    float s = (v0.x + v0.y) + (v0.z + v0.w) + (v1.x + v1.y) + (v1.z + v1.w);
    s += __shfl_xor(s, 1);
    s += __shfl_xor(s, 2);
    s += __shfl_xor(s, 4);
    s += __shfl_xor(s, 8);                             // sum over the 16-lane row group
    if ((l & 15) == 0) fs[r] = s;
  }
  __syncthreads();
  if (t < 64) part[((size_t)b * CC + c0 + t) * 32 + nt] = fs[t];
}

// ---------------- Kernel A2: sum row partials -> pooled_x raw sums --------------------
__global__ __launch_bounds__(256) void k_sumpart(const float* __restrict__ part,
                                                 float* __restrict__ px)
{
  const int g = blockIdx.x * 256 + threadIdx.x;   // 0..8191 = b*512+c
  float s = 0.f;
  #pragma unroll
  for (int i = 0; i < 32; ++i) s += part[(size_t)g * 32 + i];
  px[g] = s;
}

// ---------------- Kernel B: energy = q.qT, fp16, SYMMETRIC upper-tri ------------------
// 128x128 tile, 4 waves, BK=32, 48 KiB LDS (3 blocks/CU). Depth-2 pipeline (3 bufs).
template <int KSPLIT>
__global__ __launch_bounds__(256, 3) void k_energy(
    const unsigned short* __restrict__ qh,
    float* __restrict__ EP)
{
  const int bx  = blockIdx.x;               // 160*KSPLIT blocks
  const int xcd = bx & 7;
  const int j   = bx >> 3;
  const int gi  = j / 10;
  const int t10 = j % 10;
  const int g   = xcd + (gi << 3);          // group = b*KSPLIT+ks, grouped per XCD
  const int b   = g / KSPLIT;
  const int ks  = g % KSPLIT;
  int tr, tc;
  if (t10 < 4)      { tr = 0; tc = t10; }
  else if (t10 < 7) { tr = 1; tc = t10 - 3; }
  else if (t10 < 9) { tr = 2; tc = t10 - 5; }
  else              { tr = 3; tc = 3; }
  const bool diag = (tr == tc);
  const int kbase = ks * (NN / KSPLIT);
  const int NK    = 128 / KSPLIT;           // K-steps of 32

  const int t = threadIdx.x, w = t >> 6, l = t & 63;
  const int wr = w >> 1, wc = w & 1;

  __shared__ short lds[3][2][128 * 32];     // [buf][A,B] = 48 KiB

  const size_t qoff = (size_t)b * CC * NN;
  const unsigned short* sA = qh + qoff + (size_t)(tr * 128) * NN;
  const unsigned short* sB = diag ? sA : qh + qoff + (size_t)(tc * 128) * NN;

  const int r1 = w * 16 + (l >> 2);
  const int kl = (((l & 3) ^ (l >> 4)) << 3);          // pre-swizzled source k offset
  const int d1 = w * 512;
  const int d2 = 2048 + w * 512;
  const int laneoff = ((l & 15) << 5) + ((((l >> 4) ^ ((l >> 2) & 3))) << 3);

  f32x4 acc[4][4] = {};

  auto stage = [&](int buf, int kk) {       // always 4 loads (uniform vmcnt)
    const int k0 = kbase + kk * 32 + kl;
    gload16(sA + (size_t)r1 * NN + k0,        &lds[buf][0][d1]);
    gload16(sA + (size_t)(r1 + 64) * NN + k0, &lds[buf][0][d2]);
    gload16(sB + (size_t)r1 * NN + k0,        &lds[buf][1][d1]);
    gload16(sB + (size_t)(r1 + 64) * NN + k0, &lds[buf][1][d2]);
  };

  stage(0, 0);
  stage(1, 1);
  VMCNT(4);
  __builtin_amdgcn_s_barrier();

  for (int kk = 0; kk < NK; ++kk) {
    const int cur = kk % 3;
    if (kk + 2 < NK) stage((kk + 2) % 3, kk + 2);
    const short* A = &lds[cur][0][0];
    const short* Bm = &lds[cur][1][0];
    f16x8 ah[4], bh[4];
    #pragma unroll
    for (int m = 0; m < 4; ++m)
      ah[m] = *(const f16x8*)(A + (wr * 64 + m * 16) * 32 + laneoff);
    #pragma unroll
    for (int n = 0; n < 4; ++n)
      bh[n] = *(const f16x8*)(Bm + (wc * 64 + n * 16) * 32 + laneoff);
    __builtin_amdgcn_s_setprio(1);
    #pragma unroll
    for (int m = 0; m < 4; ++m)
      #pragma unroll
      for (int n = 0; n < 4; ++n)
        acc[m][n] = __builtin_amdgcn_mfma_f32_16x16x32_f16(ah[m], bh[n], acc[m][n], 0, 0, 0);
    __builtin_amdgcn_s_setprio(0);
    if (kk + 2 < NK)      VMCNT(4);
    else if (kk + 1 < NK) VMCNT(0);
    __builtin_amdgcn_s_barrier();
  }

  const int row0 = tr * 128 + wr * 64, col0 = tc * 128 + wc * 64;
  float* Eb = EP + ((size_t)ks * BB + b) * CC * CC;
  #pragma unroll
  for (int m = 0; m < 4; ++m)
    #pragma unroll
    for (int n = 0; n < 4; ++n)
      #pragma unroll
      for (int r = 0; r < 4; ++r) {
        const int row = row0 + m * 16 + ((l >> 4) << 2) + r;
        const int col = col0 + n * 16 + (l & 15);
        const float v = acc[m][n][r];
        Eb[(size_t)row * CC + col] = v;
        if (!diag) Eb[(size_t)col * CC + row] = v;
      }
}

// ---------------- Kernel C: att = softmax(-E) per row; pooled_out = att . mean_x ------
template <int NP>
__global__ __launch_bounds__(64) void k_softmax(
    const float* __restrict__ EP, const float* __restrict__ px,
    unsigned short* __restrict__ att, float* __restrict__ po)
{
  const int bx = blockIdx.x;                  // 8192 = b*512+c
  const int b = bx >> 9, c = bx & 511;
  const int l = threadIdx.x;
  const size_t row4 = (((size_t)b * CC + c) * CC) >> 2;   // float4 index of row start
  const size_t PS4 = ((size_t)BB * CC * CC) >> 2;
  const float4* E4 = (const float4*)EP;

  float v[8];
  {
    float4 a = E4[row4 + 2 * l];
    float4 bq = E4[row4 + 2 * l + 1];
    #pragma unroll
    for (int p = 1; p < NP; ++p) {
      const float4 a2 = E4[(size_t)p * PS4 + row4 + 2 * l];
      const float4 b2 = E4[(size_t)p * PS4 + row4 + 2 * l + 1];
      a.x += a2.x; a.y += a2.y; a.z += a2.z; a.w += a2.w;
      bq.x += b2.x; bq.y += b2.y; bq.z += b2.z; bq.w += b2.w;
    }
    v[0] = a.x; v[1] = a.y; v[2] = a.z; v[3] = a.w;
    v[4] = bq.x; v[5] = bq.y; v[6] = bq.z; v[7] = bq.w;
  }
  float mn = v[0];
  #pragma unroll
  for (int i = 1; i < 8; ++i) mn = fminf(mn, v[i]);
  #pragma unroll
  for (int o = 32; o > 0; o >>= 1) mn = fminf(mn, __shfl_xor(mn, o));
  float s = 0.f;
  #pragma unroll
  for (int i = 0; i < 8; ++i) { v[i] = __expf(mn - v[i]); s += v[i]; }
  float dot;
  {
    const float4* px4 = (const float4*)(px + (size_t)b * CC);
    const float4 p0 = px4[2 * l];
    const float4 p1 = px4[2 * l + 1];
    dot = v[0] * p0.x + v[1] * p0.y + v[2] * p0.z + v[3] * p0.w
        + v[4] * p1.x + v[5] * p1.y + v[6] * p1.z + v[7] * p1.w;
  }
  #pragma unroll
  for (int o = 32; o > 0; o >>= 1) { s += __shfl_xor(s, o); dot += __shfl_xor(dot, o); }
  const float inv = 1.f / s;
  uint4 pkv;
  pkv.x = pk2(v[0] * inv, v[1] * inv);
  pkv.y = pk2(v[2] * inv, v[3] * inv);
  pkv.z = pk2(v[4] * inv, v[5] * inv);
  pkv.w = pk2(v[6] * inv, v[7] * inv);
  ((uint4*)(att + ((size_t)b * CC + c) * CC))[l] = pkv;   // 16 B store, 8 halves
  if (l == 0) po[(size_t)b * CC + c] = dot / (s * 4096.f);
}

// ---------------- Kernel D: SE MLP -> se[b][c] -----------------------------------------
__global__ __launch_bounds__(256) void k_mlp(
    const float* __restrict__ px, const float* __restrict__ po,
    const float* __restrict__ w1, const float* __restrict__ b1,
    const float* __restrict__ w2, const float* __restrict__ b2,
    float* __restrict__ se)
{
  const int b = blockIdx.x, t = threadIdx.x;
  __shared__ float p[1024];
  __shared__ float hp[64][5];
  __shared__ float h[64];
  for (int i = t; i < 1024; i += 256)
    p[i] = (i < 512) ? px[(size_t)b * 512 + i] * (1.f / 4096.f)
                     : po[(size_t)b * 512 + i - 512];
  __syncthreads();
  {
    const int j = t >> 2, q = t & 3;
    float s = 0.f;
    const float* wr = w1 + (size_t)j * 1024 + q * 256;
    const float* pp = p + q * 256;
    for (int k = 0; k < 256; ++k) s += pp[k] * wr[k];
    hp[j][q] = s;
  }
  __syncthreads();
  if (t < 64) h[t] = fmaxf(hp[t][0] + hp[t][1] + hp[t][2] + hp[t][3] + b1[t], 0.f);
  __syncthreads();
  for (int c = t; c < 512; c += 256) {
    float s = b2[c];
    for (int j = 0; j < 64; ++j) s += h[j] * w2[(size_t)c * 64 + j];
    se[(size_t)b * 512 + c] = 1.f / (1.f + __expf(-s));
  }
}

// ---------------- Kernel E: out = att @ q, fused blend se*x + (1-se)*out --------------
// 8-wave 128x256 tile, 1024 blocks, 72 KB LDS (2 blocks/CU), depth-2 counted vmcnt.
// B (q^T) comes straight from qh via ds_read_b64_tr_b16 (no qt tensor).
//   Chunk layout per buf: 16 chunks of [32 d-permuted x 16 n], perm position p holds
//   d = (s&3)*8 + (s>>2)*4 + r (s=p>>2, r=p&3). gload16 stages linearly with the
//   inverse-permuted per-lane GLOBAL source (lane i -> d=perm[i>>1], n=8*(i&1)).
//   tr_read: per-lane addr = base + l*8 BYTES (R9 bug: HW adds NO lane offset);
//   out_l[j] = half[(l&15) + 16j + 64*(l>>4)] -> k = 8*(l>>4)+j after the perm.
__global__ __launch_bounds__(512, 4) void k_out(
    const unsigned short* __restrict__ att,
    const float* __restrict__ se,
    const unsigned short* __restrict__ qh,
    float* __restrict__ out)
{
  const int bx = blockIdx.x;                      // 1024 blocks, XCD-grouped per batch
  const int xcd = bx & 7;
  const int j   = bx >> 3;                        // 0..127
  const int b   = xcd + ((j >> 6) << 3);          // 2 batches per XCD
  const int tt  = j & 63;
  const int tr = tt >> 4, tc = tt & 15;           // tr: 4 x 128 c-rows; tc: 16 x 256 n
  const int t = threadIdx.x, w = t >> 6, l = t & 63;
  const int wr = w >> 2, wc = w & 3;              // wave quadrant: 2 x 4 of 64x64

  // [buf][ A:128x32 (4096 halves) | B:16 chunks x 512 halves ] = 24 KiB per buf
  __shared__ short lds[3][12288];

  const unsigned short* sA  = att + (size_t)b * CC * CC + (size_t)(tr * 128) * CC;
  const unsigned short* sBq = qh  + (size_t)b * CC * NN;
  const int n0g = tc * 256;

  // A staging (swizzled b128 path, unchanged from the verified structure)
  const int r1 = w * 16 + (l >> 2);
  const int kl = (((l & 3) ^ (l >> 4)) << 3);
  const int dA = w * 512;
  const int laneoff = ((l & 15) << 5) + ((((l >> 4) ^ ((l >> 2) & 3))) << 3);

  // B staging lane mapping: lane l -> perm position p=l>>1 -> d, n8
  const int sB_s = l >> 3;                                         // s = p>>2
  const int sB_d = ((sB_s & 3) << 3) + ((sB_s >> 2) << 2) + ((l >> 1) & 3);
  const int sB_n = (l & 1) << 3;

  const int trlane = l << 2;            // halves: l*4 = l*8 BYTES (own b64 per lane)

  f32x4 acc[4][4] = {};

  auto stage = [&](int buf, int kk) {             // 3 loads per wave (uniform vmcnt)
    gload16(sA + (size_t)r1 * CC + kk * 32 + kl, &lds[buf][dA]);
    const unsigned short* gB = sBq + (size_t)(kk * 32 + sB_d) * NN + n0g + sB_n;
    gload16(gB + (2 * w) * 16,     &lds[buf][4096 + (2 * w) * 512]);      // chunk 2w
    gload16(gB + (2 * w + 1) * 16, &lds[buf][4096 + (2 * w + 1) * 512]);  // chunk 2w+1
  };

  stage(0, 0);
  stage(1, 1);
  VMCNT(3);                                 // stage(0) landed (own wave)
  __builtin_amdgcn_s_barrier();             // -> landed for all waves

  for (int kk = 0; kk < 16; ++kk) {
    const int cur = kk % 3;
    if (kk + 2 < 16) stage((kk + 2) % 3, kk + 2);
    const short* A = &lds[cur][0];
    f16x8 af[4], bf[4];
    #pragma unroll
    for (int m = 0; m < 4; ++m) af[m] = *(const f16x8*)(A + (wr * 64 + m * 16) * 32 + laneoff);
    // B via hardware transpose read (chunks wc*4 .. wc*4+3; 2 reads per chunk)
    {
      const __attribute__((address_space(3))) short* p3 =
          (__attribute__((address_space(3))) short*)&lds[cur][4096 + wc * 2048] + trlane;
      u32x2 r0, r1v, r2, r3, r4, r5, r6, r7;
      TRREAD(r0, p3, 0);    TRREAD(r1v, p3, 512);
      TRREAD(r2, p3, 1024); TRREAD(r3, p3, 1536);
      TRREAD(r4, p3, 2048); TRREAD(r5, p3, 2560);
      TRREAD(r6, p3, 3072); TRREAD(r7, p3, 3584);
      u32x4 c0 = {r0.x, r0.y, r1v.x, r1v.y};
      u32x4 c1 = {r2.x, r2.y, r3.x, r3.y};
      u32x4 c2 = {r4.x, r4.y, r5.x, r5.y};
      u32x4 c3 = {r6.x, r6.y, r7.x, r7.y};
      bf[0] = __builtin_bit_cast(f16x8, c0);
      bf[1] = __builtin_bit_cast(f16x8, c1);
      bf[2] = __builtin_bit_cast(f16x8, c2);
      bf[3] = __builtin_bit_cast(f16x8, c3);
    }
    asm volatile("s_waitcnt lgkmcnt(0)" ::: "memory");
    __builtin_amdgcn_sched_barrier(0);           // rule #18: fence MFMA below the wait
    __builtin_amdgcn_s_setprio(1);
    #pragma unroll
    for (int m = 0; m < 4; ++m)
      #pragma unroll
      for (int n = 0; n < 4; ++n)
        acc[m][n] = __builtin_amdgcn_mfma_f32_16x16x32_f16(af[m], bf[n], acc[m][n], 0, 0, 0);
    __builtin_amdgcn_s_setprio(0);
    if (kk + 2 < 16)      VMCNT(3);   // stage(kk+1) landed; stage(kk+2) in flight
    else if (kk + 1 < 16) VMCNT(0);
    __builtin_amdgcn_s_barrier();
  }

  // ---- epilogue: per-wave LDS slab (16 rows x 68 pitch), float4-coalesced IO ----
  float* slab = (float*)(&lds[0][0]) + w * (16 * 68);
  const int row0 = tr * 128 + wr * 64, col0q = tc * 256 + wc * 64;
  const size_t xb = (size_t)b * CC * NN;
  const float* seb = se + (size_t)b * CC;
  #pragma unroll
  for (int m = 0; m < 4; ++m) {
    #pragma unroll
    for (int n = 0; n < 4; ++n)
      #pragma unroll
      for (int r = 0; r < 4; ++r)
        slab[(((l >> 4) << 2) + r) * 68 + n * 16 + (l & 15)] = acc[m][n][r];
    #pragma unroll
    for (int it = 0; it < 4; ++it) {
      const int rl = (it << 2) + (l >> 4);
      const int c  = row0 + m * 16 + rl;
      const int n4 = (l & 15) << 2;
      const float4 a = *(const float4*)&slab[rl * 68 + n4];
      const float sv = seb[c];
      const float om = 1.f - sv;
      const size_t go = xb + (size_t)c * NN + col0q + n4;
      const ushort4 hx = *(const ushort4*)(qh + go);
      float4 o;
      o.x = sv * h2f(hx.x) + om * a.x;
      o.y = sv * h2f(hx.y) + om * a.y;
      o.z = sv * h2f(hx.z) + om * a.z;
      o.w = sv * h2f(hx.w) + om * a.w;
      *(float4*)(out + go) = o;
    }
  }
}

// ---------------------------------------------------------------------------------------
extern "C" void kernel_launch(void* const* d_in, const int* in_sizes, int n_in,
                              void* d_out, int out_size, void* d_ws, size_t ws_size,
                              hipStream_t stream) {
  (void)in_sizes; (void)n_in; (void)out_size;
  const float* x  = (const float*)d_in[0];
  const float* w1 = (const float*)d_in[1];
  const float* b1 = (const float*)d_in[2];
  const float* w2 = (const float*)d_in[3];
  const float* b2 = (const float*)d_in[4];
  float* out = (float*)d_out;

  const size_t O_QH  = 0;                       // 67,108,864 (fp16 q)
  const size_t O_EP  = 67108864;                // KSPLIT x 16,777,216 (fp32 E partials)
  const size_t EPSZ1 = 16777216;

  // tail: att(8,388,608) + part(1,048,576) + px/po/se(3*32768)
  const size_t TAIL = 8388608 + 1048576 + 3 * 32768;     // 9,535,488
  const size_t NEED1 = O_EP + 1 * EPSZ1 + TAIL;
  const size_t NEED2 = O_EP + 2 * EPSZ1 + TAIL;
  const size_t NEED4 = O_EP + 4 * EPSZ1 + TAIL;

  if (ws_size < NEED1) return;   // fail loudly (output stays poisoned)
  const int ksplit = (ws_size >= NEED4) ? 4 : (ws_size >= NEED2) ? 2 : 1;

  char* ws = (char*)d_ws;
  unsigned short* qh  = (unsigned short*)(ws + O_QH);
  float*          EP  = (float*)(ws + O_EP);
  char* tail          = ws + O_EP + (size_t)ksplit * EPSZ1;
  unsigned short* att = (unsigned short*)(tail);
  float*          part= (float*)(tail + 8388608);
  float*          px  = (float*)(tail + 9437184);
  float*          po  = (float*)(tail + 9469952);
  float*          se  = (float*)(tail + 9502720);

  k_convert<<<dim3(32, 8, 16), 256, 0, stream>>>(x, qh, part);
  k_sumpart<<<32, 256, 0, stream>>>(part, px);
  if (ksplit == 4) {
    k_energy<4><<<640, 256, 0, stream>>>(qh, EP);
    k_softmax<4><<<8192, 64, 0, stream>>>(EP, px, att, po);
  } else if (ksplit == 2) {
    k_energy<2><<<320, 256, 0, stream>>>(qh, EP);
    k_softmax<2><<<8192, 64, 0, stream>>>(EP, px, att, po);
  } else {
    k_energy<1><<<160, 256, 0, stream>>>(qh, EP);
    k_softmax<1><<<8192, 64, 0, stream>>>(EP, px, att, po);
  }
  k_mlp<<<16, 256, 0, stream>>>(px, po, w1, b1, w2, b2, se);
  k_out<<<1024, 512, 0, stream>>>(att, se, qh, out);
}